// Round 1
// baseline (241.780 us; speedup 1.0000x reference)
//
#include <hip/hip_runtime.h>

#define NB 32
#define NC 511      // T-1 context positions
#define NK 8        // senses (center)
#define NS 8        // senses (context)
#define ND 300      // embedding dim
#define ND4 75      // float4 per row
#define NCH 16      // c-chunks for m-tilde partials
#define CCHUNK 32
#define EPS_COS 1e-8f

// Math notes (verified R1-R6, absmax 0.0):
//  - positional log-weight is constant (dist>=1 -> exp(-1000*d) underflows ->
//    log(EPS)), cancels in softmax over c => center_pos/query_token_ids unused.
//  - cosine(cen,m) is scale-invariant in m => softmax normalization and max-
//    subtraction cancel; accumulate unnormalized m~ = sum_c exp(a_c) * v_c.
//  - R6 post-mortem: every structure plateaus at 1.8-2.5 TB/s LOGICAL reads
//    while physical HBM is ~0.85 TB/s => issue/latency-bound, not BW-bound.
//  - R9 (this version): shrink K1's post-load instruction tail (48 shfl+48 add
//    -> 10 shfl + ~24 VALU distributed butterfly; 8-lane coalesced ea store in
//    [b,c,k] layout; exp spread over 8 lanes) and 8x the parallelism of the
//    final reduction (k_final split into k_s: 256 blocks over (b,k), and
//    k_fin: trivial softmax/argmax/pooled).

typedef float nfloat4 __attribute__((ext_vector_type(4)));

__device__ __forceinline__ void n4add(nfloat4& a, const nfloat4& b) { a += b; }

// ---------------------------------------------------------------------------
// K1: one wave per (b,c). Batched NT loads -> tree mean -> v; 8 dots vs cen;
// distributed exchange-butterfly reduce (lane l ends with total for k=l&7);
// ea = exp(a/sqrt(d)) written [b,c,k] by lanes 0..7 (one 32B coalesced store).
// Reads ctx once (157 MB) — the BW-critical pass.
// ---------------------------------------------------------------------------
__global__ __launch_bounds__(256) void k_va(const float* __restrict__ ctx,
                                            const float* __restrict__ cen,
                                            float* __restrict__ v,
                                            float* __restrict__ ea) {
    const int b    = blockIdx.x >> 7;        // 128 blocks per b
    const int cgrp = blockIdx.x & 127;
    const int w    = threadIdx.x >> 6;       // 4 waves -> 4 c's
    const int lane = threadIdx.x & 63;
    const int c = cgrp * 4 + w;
    if (c >= NC) return;                     // wave-uniform

    const nfloat4* ctx4 = (const nfloat4*)ctx + (size_t)(b * NC + c) * NS * ND4;
    const int i0 = lane;
    const int i1 = lane + 64;
    const bool has1 = (i1 < ND4);            // lanes 0..10 own a second float4

    // ---- batched loads: 8 unmasked, then one exec-toggle block of 8 ----
    nfloat4 X[NS];
#pragma unroll
    for (int s = 0; s < NS; ++s)
        X[s] = __builtin_nontemporal_load(&ctx4[s * ND4 + i0]);
    nfloat4 Y[NS] = {};
    if (has1) {
#pragma unroll
        for (int s = 0; s < NS; ++s)
            Y[s] = __builtin_nontemporal_load(&ctx4[s * ND4 + i1]);
    }

    // ---- tree mean ----
    n4add(X[0], X[1]); n4add(X[2], X[3]); n4add(X[4], X[5]); n4add(X[6], X[7]);
    n4add(X[0], X[2]); n4add(X[4], X[6]);
    n4add(X[0], X[4]);
    n4add(Y[0], Y[1]); n4add(Y[2], Y[3]); n4add(Y[4], Y[5]); n4add(Y[6], Y[7]);
    n4add(Y[0], Y[2]); n4add(Y[4], Y[6]);
    n4add(Y[0], Y[4]);
    const float inv = 0.125f;                // 1/S
    nfloat4 s0 = X[0] * inv;
    nfloat4 s1 = Y[0] * inv;

    nfloat4* v4 = (nfloat4*)v + (size_t)(b * NC + c) * ND4;
    v4[i0] = s0;
    if (has1) v4[i1] = s1;

    // ---- 8 dots vs cen (L1-resident after first block) ----
    const nfloat4* cen4 = (const nfloat4*)cen + (size_t)b * NK * ND4;
    float pk[NK];
#pragma unroll
    for (int k = 0; k < NK; ++k) {
        nfloat4 ca = cen4[k * ND4 + i0];
        float p = ca.x * s0.x + ca.y * s0.y + ca.z * s0.z + ca.w * s0.w;
        if (has1) {
            nfloat4 cb = cen4[k * ND4 + i1];
            p += cb.x * s1.x + cb.y * s1.y + cb.z * s1.z + cb.w * s1.w;
        }
        pk[k] = p;
    }

    // ---- distributed exchange-butterfly: lane l -> total for k = l&7 ----
    // stage 0 (xor 1): pairs (0,1)(2,3)(4,5)(6,7); keep the one matching bit0
    const bool b0 = (lane & 1) != 0;
    float r[4];
#pragma unroll
    for (int j = 0; j < 4; ++j) {
        float keep = b0 ? pk[2 * j + 1] : pk[2 * j];
        float send = b0 ? pk[2 * j]     : pk[2 * j + 1];
        r[j] = keep + __shfl_xor(send, 1);
    }
    // stage 1 (xor 2): (r0,r1)(r2,r3); select by bit1
    const bool b1 = (lane & 2) != 0;
    float q0, q1;
    { float keep = b1 ? r[1] : r[0]; float send = b1 ? r[0] : r[1];
      q0 = keep + __shfl_xor(send, 2); }
    { float keep = b1 ? r[3] : r[2]; float send = b1 ? r[2] : r[3];
      q1 = keep + __shfl_xor(send, 2); }
    // stage 2 (xor 4): (q0,q1); select by bit2
    const bool b2 = (lane & 4) != 0;
    float u;
    { float keep = b2 ? q1 : q0; float send = b2 ? q0 : q1;
      u = keep + __shfl_xor(send, 4); }
    // stages 3-5: plain folds over lanes 8/16/32 (same k within each octet)
    u += __shfl_xor(u, 8);
    u += __shfl_xor(u, 16);
    u += __shfl_xor(u, 32);

    if (lane < NK) {
        const float scale = 0.057735026919f; // 1/sqrt(300)
        ea[((size_t)(b * NC) + c) * NK + lane] = __expf(u * scale);
    }
}

// ---------------------------------------------------------------------------
// K2: m~ partials over c-chunks: part[ch,b,k,:] = sum_{c in chunk} ea * v[b,c,:].
// 512 blocks (2/CU); ea tile in LDS (broadcast reads). v is L2/L3-warm.
// ea layout is now [b,c,k] -> one fully-contiguous 1KB LDS fill.
// ---------------------------------------------------------------------------
__global__ __launch_bounds__(320) void k_m(const float* __restrict__ v,
                                           const float* __restrict__ ea,
                                           float* __restrict__ part) {
    int b  = blockIdx.x >> 4;
    int ch = blockIdx.x & 15;
    int c0 = ch * CCHUNK;
    int cn = min(CCHUNK, NC - c0);
    __shared__ float al[CCHUNK][NK];
    int t = threadIdx.x;
    if (t < NK * CCHUNK) {             // 256 contiguous loads
        int cc = t >> 3, k = t & 7;
        al[cc][k] = (cc < cn) ? ea[((size_t)(b * NC) + c0 + cc) * NK + k] : 0.f;
    }
    __syncthreads();
    if (t < ND) {
        float acc[NK] = {0.f, 0.f, 0.f, 0.f, 0.f, 0.f, 0.f, 0.f};
        const float* vp = v + ((size_t)b * NC + c0) * ND + t;
        for (int cc = 0; cc < cn; ++cc) {
            float vv = vp[(size_t)cc * ND];
#pragma unroll
            for (int k = 0; k < NK; ++k) acc[k] += al[cc][k] * vv;
        }
        float* pp = part + ((size_t)(ch * NB + b) * NK) * ND + t;
#pragma unroll
        for (int k = 0; k < NK; ++k) pp[(size_t)k * ND] = acc[k];
    }
}

// ---------------------------------------------------------------------------
// K3a: one block per (b,k): sum the 16 m~ partials along d, cosine vs cen row.
// 256 blocks (1/CU) — 8x the parallelism of the old 32-block k_final.
// ---------------------------------------------------------------------------
__global__ __launch_bounds__(320) void k_s(const float* __restrict__ part,
                                           const float* __restrict__ cen,
                                           float* __restrict__ sred) {
    const int bk = blockIdx.x;           // b*NK + k
    const int b  = bk >> 3;
    const int k  = bk & 7;
    const int t  = threadIdx.x;
    float num = 0.f, n1 = 0.f, n2 = 0.f;
    if (t < ND) {
        float mval = 0.f;
#pragma unroll
        for (int ch = 0; ch < NCH; ++ch)
            mval += part[((size_t)(ch * NB + b) * NK + k) * ND + t];
        float cv = cen[(size_t)bk * ND + t];
        num = cv * mval; n1 = cv * cv; n2 = mval * mval;
    }
#pragma unroll
    for (int off = 32; off; off >>= 1) {
        num += __shfl_down(num, off);
        n1  += __shfl_down(n1, off);
        n2  += __shfl_down(n2, off);
    }
    __shared__ float red[3][5];
    int w = t >> 6, lane = t & 63;
    if (lane == 0) { red[0][w] = num; red[1][w] = n1; red[2][w] = n2; }
    __syncthreads();
    if (t == 0) {
        float a = red[0][0] + red[0][1] + red[0][2] + red[0][3] + red[0][4];
        float x = red[1][0] + red[1][1] + red[1][2] + red[1][3] + red[1][4];
        float y = red[2][0] + red[2][1] + red[2][2] + red[2][3] + red[2][4];
        float denom = fmaxf(sqrtf(x), EPS_COS) * fmaxf(sqrtf(y), EPS_COS);
        sred[bk] = a / denom;
    }
}

// ---------------------------------------------------------------------------
// K3b: per b (tiny): softmax over 8 cosines, first-max argmax, write q + pooled.
// ---------------------------------------------------------------------------
__global__ __launch_bounds__(64) void k_fin(const float* __restrict__ sred,
                                            const float* __restrict__ cen,
                                            float* __restrict__ out) {
    const int b = blockIdx.x;
    const int t = threadIdx.x;
    float sv = (t < NK) ? sred[b * NK + t] : -3.0e38f;
    // 8-lane-group reductions (xor 4/2/1 stays inside each octet)
    float mx = sv;
#pragma unroll
    for (int off = 4; off; off >>= 1) mx = fmaxf(mx, __shfl_xor(mx, off));
    float e = __expf(sv - mx);
    float sum = e;
#pragma unroll
    for (int off = 4; off; off >>= 1) sum += __shfl_xor(sum, off);
    int cand = (t < NK && sv == mx) ? t : NK;   // first-max argmax
#pragma unroll
    for (int off = 4; off; off >>= 1) cand = min(cand, __shfl_xor(cand, off));
    if (t < NK) out[(size_t)NB * ND + b * NK + t] = e / sum;
    const int best = __shfl(cand, 0);           // broadcast from octet 0
    const float* src = cen + (size_t)(b * NK + best) * ND;
    for (int idx = t; idx < ND; idx += 64)
        out[(size_t)b * ND + idx] = src[idx];
}

extern "C" void kernel_launch(void* const* d_in, const int* in_sizes, int n_in,
                              void* d_out, int out_size, void* d_ws, size_t ws_size,
                              hipStream_t stream) {
    // d_in[0]=center_pos, d_in[1]=query_token_ids: unused (log-weight constant)
    const float* cen = (const float*)d_in[2];   // [B,K,d]
    const float* ctx = (const float*)d_in[3];   // [B,C,S,d]
    float* out = (float*)d_out;                 // pooled [B,d] then q [B,K]

    float* v    = (float*)d_ws;                       // B*C*D      floats
    float* ea   = v + (size_t)NB * NC * ND;           // B*C*K      floats ([b,c,k])
    float* part = ea + (size_t)NB * NC * NK;          // NCH*B*K*D  floats
    float* sred = part + (size_t)NCH * NB * NK * ND;  // B*K        floats

    k_va<<<dim3(NB * 128), dim3(256), 0, stream>>>(ctx, cen, v, ea);
    k_m<<<dim3(NB * NCH), dim3(320), 0, stream>>>(v, ea, part);
    k_s<<<dim3(NB * NK), dim3(320), 0, stream>>>(part, cen, sred);
    k_fin<<<dim3(NB), dim3(64), 0, stream>>>(sred, cen, out);
}